// Round 9
// baseline (255.862 us; speedup 1.0000x reference)
//
#include <hip/hip_runtime.h>

// VQ nearest-codebook, round 9: flat decomposition — no K-round loop.
// prep pre-swizzles BOTH codebook and x into MFMA fragment layout in ws.
// vq_partial: 7680 tiny blocks (band,batch,ttile128,kslice128), ONE barrier,
// 96 MFMA/wave, partials (m1,m2,idx) to ws. vq_merge: merge 8 kslices,
// margin-check + exact fp32 rescue, transposed gather epilogue.
//
// x: (2, 40, 64, 1500) f32 ; cb: (40, 1024, 64) f32
// out[b,band,c,t] = cb[band, argmin_k ||x[b,band,:,t]-cb[band,k]||^2, c]

#define NBAND  40
#define CH     64
#define TT     1500
#define NCODE  1024
#define MT     128
#define NTILE  12      // 12*128 = 1536
#define NTG    48      // 32-row t-groups allocated (47 used)
#define THRESH 1e-3f   // rescue margin; bf16-split err bound ~2e-4

typedef short v8s __attribute__((ext_vector_type(8)));
typedef float v4f __attribute__((ext_vector_type(4)));

// ws layout:
//  CBF: [band][group 0..31][plane 0..7][lane 0..63][8 ushort]   (10,485,760 B)
//  XF : [batch*40+band][tg 0..47][plane 0..7][lane 0..63][8 ushort] (31,457,280 B)
//       plane = split*4 + mi*2 + ks ; lane=quad*16+col ; elem j:
//       value = split(x[b][band][c=ks*32+quad*8+j][t=tg*32+mi*16+col])
//  C2 : float[40*1024]
//  PB : u64 [batch*40+band][kslice 0..7][ti 0..1535]  packed (ordScore,idx)
//  PS : f32 same shape  (second-min within kslice)
#define CBF_BYTES  ((size_t)NBAND * 32 * 8 * 64 * 8 * 2)
#define XF_OFF     CBF_BYTES
#define XF_BYTES   ((size_t)2 * NBAND * NTG * 8 * 64 * 8 * 2)
#define C2_OFF     (XF_OFF + XF_BYTES)
#define C2_BYTES   ((size_t)NBAND * NCODE * 4)
#define PB_OFF     (C2_OFF + C2_BYTES)
#define PB_BYTES   ((size_t)2 * NBAND * 8 * 1536 * 8)
#define PS_OFF     (PB_OFF + PB_BYTES)
#define PS_BYTES   (PB_BYTES / 2)
#define WS_NEEDED  (PS_OFF + PS_BYTES)

__device__ __forceinline__ unsigned short f2bf(float f) {
    unsigned u = __float_as_uint(f);
    return (unsigned short)((u + 0x7FFFu + ((u >> 16) & 1u)) >> 16);   // RNE
}
__device__ __forceinline__ float bf2f(unsigned short h) {
    return __uint_as_float(((unsigned)h) << 16);
}
__device__ __forceinline__ unsigned ford(float f) {
    unsigned u = __float_as_uint(f);
    return (u & 0x80000000u) ? ~u : (u | 0x80000000u);
}
__device__ __forceinline__ float finv(unsigned u) {
    return (u & 0x80000000u) ? __uint_as_float(u & 0x7FFFFFFFu) : __uint_as_float(~u);
}
__device__ __forceinline__ unsigned long long packsk(float f, unsigned k) {
    return ((unsigned long long)ford(f) << 32) | (unsigned long long)k;
}
__device__ __forceinline__ float med3f(float a, float b, float c) {
#if __has_builtin(__builtin_amdgcn_fmed3f)
    return __builtin_amdgcn_fmed3f(a, b, c);
#else
    return fminf(fmaxf(a, b), c);
#endif
}

typedef __attribute__((address_space(1))) const unsigned char* gas_p;
typedef __attribute__((address_space(3))) unsigned char*       las_p;
__device__ __forceinline__ void async_ld16(const void* g, void* l) {
    __builtin_amdgcn_global_load_lds((gas_p)g, (las_p)l, 16, 0, 0);
}

// ---------------- prep A: codebook split+swizzle (XCD-pinned) ----------------
__global__ __launch_bounds__(256)
void vq_prep_cb(const float* __restrict__ cb,
                unsigned short* __restrict__ CBF,
                float* __restrict__ C2) {
    const int id     = blockIdx.x;              // 320
    const int v      = id >> 3;
    const int band   = (id & 7) + 8 * (v % 5);
    const int gchunk = v / 5;                   // 0..7
    const int g      = gchunk * 4 + (threadIdx.x >> 6);
    const int lane   = threadIdx.x & 63;
    const int col    = lane & 15;
    const int quad   = lane >> 4;

    float sq[2] = {0.f, 0.f};
    #pragma unroll
    for (int l = 0; l < 4; ++l) {
        const int ni = l >> 1, ks = l & 1;
        const int code = g * 32 + ni * 16 + col;
        const int c0   = ks * 32 + quad * 8;
        const float* src = cb + ((size_t)(band * NCODE + code)) * CH + c0;
        const float4 v0 = *(const float4*)src;
        const float4 v1 = *(const float4*)(src + 4);
        const float vv[8] = {v0.x, v0.y, v0.z, v0.w, v1.x, v1.y, v1.z, v1.w};
        union { unsigned short u[8]; v8s v; } hh, ll;
        #pragma unroll
        for (int j = 0; j < 8; ++j) {
            const unsigned short h = f2bf(vv[j]);
            hh.u[j] = h;
            ll.u[j] = f2bf(vv[j] - bf2f(h));
            sq[ni] = fmaf(vv[j], vv[j], sq[ni]);
        }
        const size_t gb = (size_t)(band * 32 + g) * 8;
        *(v8s*)&CBF[(gb + l)     * 512 + lane * 8] = hh.v;
        *(v8s*)&CBF[(gb + 4 + l) * 512 + lane * 8] = ll.v;
    }
    #pragma unroll
    for (int ni = 0; ni < 2; ++ni) {
        sq[ni] += __shfl_xor(sq[ni], 16);
        sq[ni] += __shfl_xor(sq[ni], 32);
    }
    if (quad == 0) {
        C2[band * NCODE + g * 32 + col]      = sq[0];
        C2[band * NCODE + g * 32 + 16 + col] = sq[1];
    }
}

// ---------------- prep B: x split+swizzle into A-fragment layout ----------------
__global__ __launch_bounds__(256)
void vq_prep_x(const float* __restrict__ x,
               unsigned short* __restrict__ XF) {
    // 480 blocks: xcd = id&7, band = xcd+8*(v%5), v=id>>3; u=v/5: batch=u&1, chunk=u>>1 (0..5)
    const int id    = blockIdx.x;
    const int v     = id >> 3;
    const int band  = (id & 7) + 8 * (v % 5);
    const int u     = v / 5;
    const int batch = u & 1;
    const int chunk = u >> 1;                   // 0..5 -> tg chunk*8..+7
    const int bb    = batch * NBAND + band;

    const int wave = threadIdx.x >> 6;
    const int lane = threadIdx.x & 63;
    const int quad = lane >> 4;
    const int col  = lane & 15;

    #pragma unroll
    for (int i = 0; i < 2; ++i) {
        const int tg = chunk * 8 + wave * 2 + i;     // 0..47
        #pragma unroll
        for (int pp = 0; pp < 4; ++pp) {
            const int mi = pp >> 1, ks = pp & 1;
            const int t  = tg * 32 + mi * 16 + col;
            union { unsigned short u[8]; v8s v; } hh, ll;
            #pragma unroll
            for (int j = 0; j < 8; ++j) {
                const int c = ks * 32 + quad * 8 + j;
                const float val = (t < TT) ? x[((size_t)bb * CH + c) * TT + t] : 0.f;
                const unsigned short h = f2bf(val);
                hh.u[j] = h;
                ll.u[j] = f2bf(val - bf2f(h));
            }
            const size_t base = ((size_t)bb * NTG + tg) * 8;
            *(v8s*)&XF[(base + pp)     * 512 + lane * 8] = hh.v;
            *(v8s*)&XF[(base + 4 + pp) * 512 + lane * 8] = ll.v;
        }
    }
}

// ---------------- main: one barrier, 96 MFMA/wave, partials out ----------------
__global__ __launch_bounds__(256, 4)
void vq_partial(const unsigned short* __restrict__ XF,
                const unsigned short* __restrict__ CBF,
                const float* __restrict__ C2f,
                unsigned long long* __restrict__ PB,
                float* __restrict__ PS) {
    __shared__ alignas(16) unsigned short LBUF[4 * 8 * 512];   // 32 KB B-frags

    // 7680 blocks: xcd = id&7; band = xcd+8*(v%5); u=v/5 (0..191):
    // batch = u&1; u2=u>>1: tile = u2%12; kslice = u2/12 (0..7)
    const int id     = blockIdx.x;
    const int v      = id >> 3;
    const int band   = (id & 7) + 8 * (v % 5);
    const int u      = v / 5;
    const int batch  = u & 1;
    const int u2     = u >> 1;
    const int tile   = u2 % NTILE;
    const int kslice = u2 / NTILE;
    const int bb     = batch * NBAND + band;

    const int tid  = threadIdx.x;
    const int wave = tid >> 6;
    const int lane = tid & 63;
    const int quad = lane >> 4;
    const int col  = lane & 15;

    // stage B: wave w stages planes fp = w*8 .. w*8+7 (gi = fp>>3, p = fp&7)
    {
        const unsigned short* cbase =
            CBF + ((size_t)(band * 32 + kslice * 4) * 8) * 512 + (size_t)lane * 8;
        #pragma unroll
        for (int i = 0; i < 8; ++i) {
            const int fp = wave * 8 + i;
            async_ld16(cbase + (size_t)fp * 512, LBUF + (size_t)fp * 512 + lane * 8);
        }
    }
    // A fragments direct global -> registers (pre-swizzled; coalesced dwordx4)
    v8s ah[2][2], al[2][2];
    {
        const int tg = tile * 4 + wave;     // 0..47
        const unsigned short* xb =
            XF + (((size_t)bb * NTG + tg) * 8) * 512 + (size_t)lane * 8;
        #pragma unroll
        for (int mi = 0; mi < 2; ++mi)
            #pragma unroll
            for (int ks = 0; ks < 2; ++ks) {
                ah[mi][ks] = *(const v8s*)(xb + (mi * 2 + ks) * 512);
                al[mi][ks] = *(const v8s*)(xb + (4 + mi * 2 + ks) * 512);
            }
    }
    __syncthreads();   // B staged (vmcnt drain) -- the ONLY barrier

    float m1[8], m2[8];
    int   id8[8];
    #pragma unroll
    for (int i = 0; i < 8; ++i) { m1[i] = 3.4028235e38f; m2[i] = 3.4028235e38f; id8[i] = 0x7fffffff; }

    #pragma unroll
    for (int gi = 0; gi < 4; ++gi) {
        const unsigned short* lb = LBUF + gi * 4096 + lane * 8;
        #pragma unroll
        for (int ni = 0; ni < 2; ++ni) {
            v4f acc[2];
            acc[0] = (v4f){0.f, 0.f, 0.f, 0.f};
            acc[1] = (v4f){0.f, 0.f, 0.f, 0.f};
            #pragma unroll
            for (int ks = 0; ks < 2; ++ks) {
                const v8s bh = *(const v8s*)(lb + (ni * 2 + ks) * 512);
                acc[0] = __builtin_amdgcn_mfma_f32_16x16x32_bf16(ah[0][ks], bh, acc[0], 0, 0, 0);
                acc[1] = __builtin_amdgcn_mfma_f32_16x16x32_bf16(ah[1][ks], bh, acc[1], 0, 0, 0);
                acc[0] = __builtin_amdgcn_mfma_f32_16x16x32_bf16(al[0][ks], bh, acc[0], 0, 0, 0);
                acc[1] = __builtin_amdgcn_mfma_f32_16x16x32_bf16(al[1][ks], bh, acc[1], 0, 0, 0);
                const v8s bl = *(const v8s*)(lb + (4 + ni * 2 + ks) * 512);
                acc[0] = __builtin_amdgcn_mfma_f32_16x16x32_bf16(ah[0][ks], bl, acc[0], 0, 0, 0);
                acc[1] = __builtin_amdgcn_mfma_f32_16x16x32_bf16(ah[1][ks], bl, acc[1], 0, 0, 0);
            }
            const int   kg  = kslice * 128 + gi * 32 + ni * 16 + col;   // global code idx
            const float c2v = C2f[band * NCODE + kg];
            // k ascending across (gi,ni) per slot -> strict '<' keeps first-min
            #pragma unroll
            for (int mi = 0; mi < 2; ++mi)
                #pragma unroll
                for (int rr = 0; rr < 4; ++rr) {
                    const int j = mi * 4 + rr;
                    const float s = fmaf(-2.f, acc[mi][rr], c2v);
                    m2[j] = med3f(s, m1[j], m2[j]);
                    const bool lt = s < m1[j];
                    m1[j]  = lt ? s : m1[j];
                    id8[j] = lt ? kg : id8[j];
                }
        }
    }

    // in-wave butterfly over 16 cols: exact (min1, idx, min2), tie -> smaller idx
    #pragma unroll
    for (int j = 0; j < 8; ++j) {
        float b1 = m1[j], b2 = m2[j];
        int   bi = id8[j];
        #pragma unroll
        for (int d = 1; d < 16; d <<= 1) {
            const float o1 = __shfl_xor(b1, d);
            const float o2 = __shfl_xor(b2, d);
            const int   oi = __shfl_xor(bi, d);
            b2 = fminf(fminf(b2, o2), fmaxf(b1, o1));
            const bool take = (o1 < b1) || (o1 == b1 && oi < bi);
            b1 = take ? o1 : b1;
            bi = take ? oi : bi;
        }
        if (col == 0) {
            const int tloc = wave * 32 + (j >> 2) * 16 + quad * 4 + (j & 3);
            const size_t off = ((size_t)bb * 8 + kslice) * 1536 + tile * MT + tloc;
            PB[off] = packsk(b1, (unsigned)bi);
            PS[off] = b2;
        }
    }
}

// ---------------- merge: 8 kslices -> winner, rescue, gather epilogue ----------------
__global__ __launch_bounds__(256)
void vq_merge(const float* __restrict__ x,
              const float* __restrict__ cb,
              const unsigned long long* __restrict__ PB,
              const float* __restrict__ PS,
              float* __restrict__ out) {
    __shared__ float OT[MT * 67];                 // 34304 B gather-transpose
    __shared__ unsigned long long best_s[MT];
    __shared__ unsigned amb_s[4];
    __shared__ float xrow_s[CH];

    // 960 blocks: xcd = id&7; band = xcd+8*(v%5); u=v/5 (0..23): batch=u&1, tile=u>>1
    const int id    = blockIdx.x;
    const int v     = id >> 3;
    const int band  = (id & 7) + 8 * (v % 5);
    const int u     = v / 5;
    const int batch = u & 1;
    const int tile  = u >> 1;                     // 0..11
    const int bb    = batch * NBAND + band;
    const int t0    = tile * MT;

    const int tid = threadIdx.x;
    if (tid < 4) amb_s[tid] = 0u;
    __syncthreads();

    if (tid < MT) {
        const size_t base = (size_t)bb * 8 * 1536 + t0 + tid;
        unsigned long long bmin = ~0ULL;
        float s1 = 3.4028235e38f, s2 = 3.4028235e38f, psmin = 3.4028235e38f;
        #pragma unroll
        for (int ks = 0; ks < 8; ++ks) {
            const unsigned long long b = PB[base + (size_t)ks * 1536];
            const float sc = finv((unsigned)(b >> 32));
            bmin = (b < bmin) ? b : bmin;         // u64 min = (score, idx) lexicographic
            s2 = med3f(sc, s1, s2);
            s1 = fminf(s1, sc);
            psmin = fminf(psmin, PS[base + (size_t)ks * 1536]);
        }
        best_s[tid] = bmin;
        const float M2 = fminf(psmin, s2);
        if ((M2 - s1) <= THRESH && t0 + tid < TT)
            atomicOr(&amb_s[tid >> 5], 1u << (tid & 31));
    }
    __syncthreads();

    // exact fp32 rescue for near-ties (rare)
    for (int t = 0; t < MT; ++t) {
        if ((amb_s[t >> 5] >> (t & 31)) & 1u) {
            if (tid < CH) xrow_s[tid] = x[((size_t)bb * CH + tid) * TT + t0 + t];
            if (tid == CH) best_s[t] = ~0ULL;
            __syncthreads();
            #pragma unroll
            for (int i = 0; i < 4; ++i) {
                const int k = tid * 4 + i;
                const float* crow = cb + ((size_t)(band * NCODE + k)) * CH;
                float dot = 0.f, c2e = 0.f;
                #pragma unroll 8
                for (int c = 0; c < CH; ++c) {
                    const float cv = crow[c];
                    dot = fmaf(cv, xrow_s[c], dot);
                    c2e = fmaf(cv, cv, c2e);
                }
                atomicMin(&best_s[t], packsk(fmaf(-2.f, dot, c2e), (unsigned)k));
            }
            __syncthreads();
        }
    }
    __syncthreads();

    // gather winning rows (coalesced 256B reads), transposed coalesced store
    {
        const int wave = tid >> 6;
        const int lane = tid & 63;
        #pragma unroll
        for (int rr = 0; rr < MT; rr += 4) {
            const int row = rr + wave;
            const unsigned idx = (unsigned)(best_s[row] & 0xFFFFFFFFull) & (NCODE - 1);
            OT[row * 67 + lane] = cb[((size_t)(band * NCODE + idx)) * CH + lane];
        }
        __syncthreads();
        const int tloc  = tid & 127;
        const int chalf = tid >> 7;
        if (t0 + tloc < TT) {
            float* ob = out + ((size_t)bb * CH) * TT + t0 + tloc;
            #pragma unroll
            for (int i = 0; i < 32; ++i) {
                const int c = chalf * 32 + i;
                ob[(size_t)c * TT] = OT[tloc * 67 + c];
            }
        }
    }
}

// ---------------- fallback: round-1 fp32 kernel (proven, ~290 us) ----------------
#define TN 128
#define KC 128
__global__ __launch_bounds__(256, 2)
void vq_fp32_kernel(const float* __restrict__ x,
                    const float* __restrict__ cb,
                    float* __restrict__ out) {
    __shared__ float XT_s[CH * TN];
    __shared__ float CBT_s[CH * KC];
    __shared__ float c2part[256];
    const int tile = blockIdx.x, band = blockIdx.y, batch = blockIdx.z;
    const int t0 = tile * TN;
    const int tid = threadIdx.x;
    const int tx = tid & 15, ty = tid >> 4;
    {
        const int c = tid >> 2, q = tid & 3;
        const float* src = x + ((size_t)(batch * NBAND + band) * CH + c) * TT + t0;
        #pragma unroll
        for (int i = 0; i < 8; ++i) {
            const int t = q * 32 + i * 4;
            float4 v = make_float4(0.f, 0.f, 0.f, 0.f);
            if (t0 + t < TT) v = *(const float4*)(src + t);
            *(float4*)&XT_s[c * TN + t] = v;
        }
    }
    float vmin[8]; int vidx[8];
    #pragma unroll
    for (int i = 0; i < 8; ++i) { vmin[i] = 3.4e38f; vidx[i] = 0x7fffffff; }
    for (int kc = 0; kc < NCODE; kc += KC) {
        __syncthreads();
        {
            const int k = tid >> 1, ch0 = (tid & 1) * 32;
            const float* src = cb + ((size_t)(band * NCODE + kc + k)) * CH + ch0;
            float s = 0.f;
            #pragma unroll
            for (int i = 0; i < 8; ++i) {
                const float4 v = *(const float4*)(src + i * 4);
                const int c0 = ch0 + i * 4;
                CBT_s[(c0 + 0) * KC + k] = v.x; CBT_s[(c0 + 1) * KC + k] = v.y;
                CBT_s[(c0 + 2) * KC + k] = v.z; CBT_s[(c0 + 3) * KC + k] = v.w;
                s = fmaf(v.x, v.x, s); s = fmaf(v.y, v.y, s);
                s = fmaf(v.z, v.z, s); s = fmaf(v.w, v.w, s);
            }
            c2part[tid] = s;
        }
        __syncthreads();
        float acc[8][8];
        #pragma unroll
        for (int ii = 0; ii < 8; ++ii)
            #pragma unroll
            for (int jj = 0; jj < 8; ++jj) acc[ii][jj] = 0.f;
        #pragma unroll 4
        for (int c = 0; c < CH; ++c) {
            const float4 xa0 = *(const float4*)&XT_s[c * TN + tx * 4];
            const float4 xa1 = *(const float4*)&XT_s[c * TN + 64 + tx * 4];
            const float4 cv0 = *(const float4*)&CBT_s[c * KC + ty * 4];
            const float4 cv1 = *(const float4*)&CBT_s[c * KC + 64 + ty * 4];
            const float xa[8] = {xa0.x, xa0.y, xa0.z, xa0.w, xa1.x, xa1.y, xa1.z, xa1.w};
            const float cv[8] = {cv0.x, cv0.y, cv0.z, cv0.w, cv1.x, cv1.y, cv1.z, cv1.w};
            #pragma unroll
            for (int ii = 0; ii < 8; ++ii)
                #pragma unroll
                for (int jj = 0; jj < 8; ++jj) acc[ii][jj] = fmaf(xa[ii], cv[jj], acc[ii][jj]);
        }
        #pragma unroll
        for (int jj = 0; jj < 8; ++jj) {
            const int kl = (jj < 4) ? (ty * 4 + jj) : (64 + ty * 4 + (jj - 4));
            const float c2v = c2part[2 * kl] + c2part[2 * kl + 1];
            const int kglob = kc + kl;
            #pragma unroll
            for (int ii = 0; ii < 8; ++ii) {
                const float score = fmaf(-2.f, acc[ii][jj], c2v);
                if (score < vmin[ii]) { vmin[ii] = score; vidx[ii] = kglob; }
            }
        }
    }
    __syncthreads();
    float* redv = XT_s;
    int* redi = (int*)(XT_s + TN * 16);
    int* idxs = (int*)(XT_s + TN * 32);
    #pragma unroll
    for (int ii = 0; ii < 8; ++ii) {
        const int t = (ii < 4) ? (tx * 4 + ii) : (64 + tx * 4 + (ii - 4));
        redv[t * 16 + ty] = vmin[ii];
        redi[t * 16 + ty] = vidx[ii];
    }
    __syncthreads();
    if (tid < TN) {
        float bv = redv[tid * 16]; int bi = redi[tid * 16];
        #pragma unroll
        for (int j = 1; j < 16; ++j) {
            const float v = redv[tid * 16 + j]; const int id = redi[tid * 16 + j];
            if (v < bv || (v == bv && id < bi)) { bv = v; bi = id; }
        }
        idxs[tid] = bi;
    }
    __syncthreads();
    {
        const int tloc = tid & 127, chalf = tid >> 7;
        if (t0 + tloc < TT) {
            const int idx = idxs[tloc];
            const float* crow = cb + ((size_t)(band * NCODE + idx)) * CH;
            float* ob = out + ((size_t)(batch * NBAND + band) * CH) * TT + t0 + tloc;
            #pragma unroll
            for (int i = 0; i < 32; ++i) {
                const int c = chalf * 32 + i;
                ob[(size_t)c * TT] = crow[c];
            }
        }
    }
}

extern "C" void kernel_launch(void* const* d_in, const int* in_sizes, int n_in,
                              void* d_out, int out_size, void* d_ws, size_t ws_size,
                              hipStream_t stream) {
    const float* x  = (const float*)d_in[0];
    const float* cb = (const float*)d_in[1];
    float* out = (float*)d_out;
    if (ws_size >= WS_NEEDED) {
        unsigned short* CBF = (unsigned short*)d_ws;
        unsigned short* XF  = (unsigned short*)((char*)d_ws + XF_OFF);
        float* C2           = (float*)((char*)d_ws + C2_OFF);
        unsigned long long* PB = (unsigned long long*)((char*)d_ws + PB_OFF);
        float* PS           = (float*)((char*)d_ws + PS_OFF);
        vq_prep_cb<<<dim3(320), dim3(256), 0, stream>>>(cb, CBF, C2);
        vq_prep_x <<<dim3(480), dim3(256), 0, stream>>>(x, XF);
        vq_partial<<<dim3(7680), dim3(256), 0, stream>>>(XF, CBF, C2, PB, PS);
        vq_merge  <<<dim3(960), dim3(256), 0, stream>>>(x, cb, PB, PS, out);
    } else {
        dim3 grid((TT + TN - 1) / TN, NBAND, 2);
        vq_fp32_kernel<<<grid, dim3(256), 0, stream>>>(x, cb, out);
    }
}